// Round 7
// baseline (25.725 us; speedup 1.0000x reference)
//
#include <hip/hip_runtime.h>
#include <math.h>

#define B 8
#define C 4
#define H 512
#define W 512
#define SEL 1
#define BIGI 1024       // H + W
#define NPIX (B*H*W)
#define CH 64           // rows per chunk
#define RC 8            // chunks per column
#define TC 32           // columns per block
#define NSEG 16         // segments per chunk
#define LL 4            // rows per thread (CH/NSEG)
#define CINF 3000       // "infinite" carry (any candidate > 1084 never wins)
#define G 4             // rows per row_fused block

// ---------------- local (per-chunk) vertical EDT, both polarities, u16 packed out ----------------
// carries via transposed 16-lane shuffle prefix/suffix-min (no serial phases)
__global__ __launch_bounds__(512) void col_two_level(const float* __restrict__ ytrue,
                                                     unsigned short* __restrict__ gpk,
                                                     unsigned* __restrict__ sumsD,
                                                     unsigned* __restrict__ sumsU) {
    __shared__ int sP[NSEG][TC + 1], sN[NSEG][TC + 1];     // w values (transposed reads)
    __shared__ int sCP[NSEG][TC + 1], sCN[NSEG][TC + 1];   // carries

    int blk = blockIdx.x;              // B * 16 tiles * RC = 1024
    int b   = blk >> 7;
    int rem = blk & 127;
    int jt  = rem >> 3;
    int rc  = rem & 7;
    int tid = threadIdx.x;
    int tx  = tid & (TC - 1);
    int ty  = tid >> 5;                // 0..15
    int j   = jt * TC + tx;
    int i0  = rc * CH + ty * LL;

    const float* m = ytrue + ((size_t)b * C + SEL) * H * W + j;
    int gfp[LL], gfn[LL];
    int pp = BIGI, pn = BIGI;
    #pragma unroll
    for (int r = 0; r < LL; ++r) {     // local forward scan, both polarities
        bool fg = (m[(size_t)(i0 + r) * W] != 0.0f);
        int vp = fg ? BIGI : 0;
        int vn = fg ? 0 : BIGI;
        vp = min(vp, pp + 1); gfp[r] = vp; pp = vp;
        vn = min(vn, pn + 1); gfn[r] = vn; pn = vn;
    }
    sP[ty][tx] = pp - ty * LL;         // w = lf - s*L  (prefix-min operand)
    sN[ty][tx] = pn - ty * LL;
    __syncthreads();

    int col = tid >> 4, seg = tid & 15;    // transposed view: 32 cols x 16 segs
    int wp = sP[seg][col], wn = sN[seg][col];
    #pragma unroll
    for (int d = 1; d < NSEG; d <<= 1) {   // prefix-min over segments (4 shuffle steps)
        int up = __shfl_up(wp, d, 16);
        int un = __shfl_up(wn, d, 16);
        if (seg >= d) { wp = min(wp, up); wn = min(wn, un); }
    }
    // D[seg] = seg*LL + wp : resolved forward value at segment end
    if (seg < NSEG - 1) {
        sCP[seg + 1][col] = seg * LL + wp;     // forward carry for seg+1
        sCN[seg + 1][col] = seg * LL + wn;
    } else {
        int jj = jt * TC + col;                // chunk summary D (u16|u16)
        sumsD[((size_t)(b * RC + rc)) * W + jj] =
            (unsigned)(seg * LL + wp) | ((unsigned)(seg * LL + wn) << 16);
    }
    if (seg == 0) { sCP[0][col] = BIGI; sCN[0][col] = BIGI; }
    __syncthreads();

    int cp = sCP[ty][tx], cn = sCN[ty][tx];
    int lbp = 1 << 20, lbn = 1 << 20;
    #pragma unroll
    for (int r = 0; r < LL; ++r) {     // forward fix + local backward summary
        int vp = min(gfp[r], cp + 1 + r); gfp[r] = vp; lbp = min(lbp, vp + r);
        int vn = min(gfn[r], cn + 1 + r); gfn[r] = vn; lbn = min(lbn, vn + r);
    }
    sP[ty][tx] = lbp + ty * LL;        // w2 = lb + s*L (suffix-min operand)
    sN[ty][tx] = lbn + ty * LL;
    __syncthreads();

    int w2p = sP[seg][col], w2n = sN[seg][col];
    #pragma unroll
    for (int d = 1; d < NSEG; d <<= 1) {   // suffix-min over segments
        int up = __shfl_down(w2p, d, 16);
        int un = __shfl_down(w2n, d, 16);
        if (seg + d < NSEG) { w2p = min(w2p, up); w2n = min(w2n, un); }
    }
    // U[seg] = w2p - seg*LL : final value at segment start
    if (seg > 0) {
        sCP[seg - 1][col] = w2p - seg * LL;    // backward carry for seg-1
        sCN[seg - 1][col] = w2n - seg * LL;
    } else {
        int jj = jt * TC + col;                // chunk summary U
        sumsU[((size_t)(b * RC + rc)) * W + jj] =
            (unsigned)w2p | ((unsigned)w2n << 16);
    }
    if (seg == NSEG - 1) { sCP[NSEG - 1][col] = BIGI; sCN[NSEG - 1][col] = BIGI; }
    __syncthreads();

    int pbp = sCP[ty][tx], pbn = sCN[ty][tx];
    unsigned short* op = gpk + ((size_t)b * H + i0) * W + j;
    #pragma unroll
    for (int r = LL - 1; r >= 0; --r) { // local backward pass + u16 packed store
        int vp = min(gfp[r], pbp + 1); pbp = vp;
        int vn = min(gfn[r], pbn + 1); pbn = vn;
        int fg = (vn == 0) ? 1 : 0;    // exactly one of vp,vn is 0
        int g  = vp + vn;              // the nonzero one
        op[(size_t)r * W] = (unsigned short)((g << 1) | fg);
    }
}

// ---------------- fused row EDT (4 rows/block) + boundary + sigmoid + partials ----------------
// rowpart[blk] = {mx_d2pos, mx_d2neg, sum s*posdis, sum s*negdis} (mins are exactly 0:
// bg pixels have d2pos=0, fg have d2neg=0; degenerate batches guarded in batch_final)
__global__ __launch_bounds__(512) void row_fused(const unsigned short* __restrict__ gpk,
                                                 const unsigned* __restrict__ sumsD,
                                                 const unsigned* __restrict__ sumsU,
                                                 const float* __restrict__ ypred,
                                                 float* __restrict__ rowpart) {
    __shared__ float2 s2[G][W];
    __shared__ float sw[4][8];

    int blk = blockIdx.x;                 // B*H/G = 1024
    int b = blk >> 7;
    int g = blk & 127;
    int i0 = g * G;
    int rc = i0 >> 6;                     // chunk of these G rows (CH=64, G|CH)
    int j = threadIdx.x;

    // inter-chunk carries from summaries (uniform branches; L2-resident)
    int Ap = CINF, An = CINF, Bp = CINF, Bn = CINF;
    #pragma unroll
    for (int q = 0; q < RC; ++q) {
        if (q < rc) {
            unsigned dv = sumsD[((size_t)(b * RC + q)) * W + j];
            int e = q * CH + CH - 1;
            Ap = min(Ap, (int)(dv & 0xFFFFu) - e);
            An = min(An, (int)(dv >> 16) - e);
        } else if (q > rc) {
            unsigned uv = sumsU[((size_t)(b * RC + q)) * W + j];
            int s0 = q * CH;
            Bp = min(Bp, (int)(uv & 0xFFFFu) + s0);
            Bn = min(Bn, (int)(uv >> 16) + s0);
        }
    }

    #pragma unroll
    for (int r = 0; r < G; ++r) {
        int ii = i0 + r;
        unsigned v = gpk[((size_t)b * H + ii) * W + j];
        int fg = v & 1;
        int gv = v >> 1;
        int gp = fg ? gv : 0;
        int gn = fg ? 0 : gv;
        gp = min(gp, min(Ap + ii, Bp - ii));   // cross-chunk fix (exact)
        gn = min(gn, min(An + ii, Bn - ii));
        s2[r][j] = make_float2((float)(gp * gp), (float)(gn * gn));
    }
    __syncthreads();

    float mxp = 0.f, mxn = 0.f, A = 0.f, Bv = 0.f;
    #pragma unroll
    for (int r = 0; r < G; ++r) {
        float2 v0 = s2[r][j];
        float bp = v0.x, bn = v0.y;
        for (int rr = 1; rr < W; ++rr) {      // exact outward scan, both polarities
            float r2 = (float)(rr * rr);
            if (r2 >= bp && r2 >= bn) break;  // unvisited candidates >= r2 -> exact
            int jl = j - rr, jr = j + rr;
            if (jl >= 0) { float2 u = s2[r][jl]; bp = fminf(bp, u.x + r2); bn = fminf(bn, u.y + r2); }
            if (jr < W)  { float2 u = s2[r][jr]; bp = fminf(bp, u.x + r2); bn = fminf(bn, u.y + r2); }
        }
        float posdis = sqrtf(bp);
        float negdis = sqrtf(bn);
        bool bnd = (bp == 1.0f);              // inner 4-boundary <=> d2pos == 1

        const float* yp = ypred + ((size_t)b * C * H + i0 + r) * W + j;
        float s = 0.f;
        #pragma unroll
        for (int cc = 0; cc < C; ++cc) {
            float x = yp[(size_t)cc * H * W];
            s += 1.0f / (1.0f + __expf(-x));
        }
        float se = bnd ? 0.f : s;
        mxp = fmaxf(mxp, bp); mxn = fmaxf(mxn, bn);
        A += se * posdis; Bv += se * negdis;
    }

    for (int off = 32; off >= 1; off >>= 1) {
        mxp = fmaxf(mxp, __shfl_down(mxp, off));
        mxn = fmaxf(mxn, __shfl_down(mxn, off));
        A  += __shfl_down(A, off);
        Bv += __shfl_down(Bv, off);
    }
    int wave = threadIdx.x >> 6, lane = threadIdx.x & 63;
    if (lane == 0) { sw[0][wave] = mxp; sw[1][wave] = mxn; sw[2][wave] = A; sw[3][wave] = Bv; }
    __syncthreads();
    if (threadIdx.x == 0) {
        float a0 = sw[0][0], a1 = sw[1][0], a2 = sw[2][0], a3 = sw[3][0];
        #pragma unroll
        for (int w = 1; w < 8; ++w) {
            a0 = fmaxf(a0, sw[0][w]); a1 = fmaxf(a1, sw[1][w]);
            a2 += sw[2][w]; a3 += sw[3][w];
        }
        *(float4*)(rowpart + (size_t)blk * 4) = make_float4(a0, a1, a2, a3);
    }
}

// ---------------- per-batch stats + total: one wave per batch ----------------
__global__ __launch_bounds__(512) void batch_final(const float* __restrict__ rowpart,
                                                   float* __restrict__ out) {
    __shared__ double sacc[8];
    int bw = threadIdx.x >> 6;            // wave = batch
    int lane = threadIdx.x & 63;
    const float4* rv = (const float4*)(rowpart + (size_t)bw * 128 * 4);
    float4 e0 = rv[lane];
    float4 e1 = rv[lane + 64];
    float mxp = fmaxf(e0.x, e1.x), mxn = fmaxf(e0.y, e1.y);
    float A = e0.z + e1.z, Bv = e0.w + e1.w;
    for (int off = 32; off >= 1; off >>= 1) {
        mxp = fmaxf(mxp, __shfl_down(mxp, off));
        mxn = fmaxf(mxn, __shfl_down(mxn, off));
        A  += __shfl_down(A, off);
        Bv += __shfl_down(Bv, off);
    }
    if (lane == 0) {
        float pmax = sqrtf(mxp), nmax = sqrtf(mxn);
        float invp = (pmax > 0.f) ? 1.0f / pmax : 0.0f;
        float invn = (nmax > 0.f) ? 1.0f / nmax : 0.0f;
        sacc[bw] = (pmax > 0.f) ? (double)(invn * Bv - invp * A) : 0.0;
    }
    __syncthreads();
    if (threadIdx.x == 0) {
        double tt = 0.0;
        #pragma unroll
        for (int q = 0; q < 8; ++q) tt += sacc[q];
        out[0] = (float)(tt / (double)((size_t)B * C * H * W));
    }
}

extern "C" void kernel_launch(void* const* d_in, const int* in_sizes, int n_in,
                              void* d_out, int out_size, void* d_ws, size_t ws_size,
                              hipStream_t stream) {
    const float* ypred = (const float*)d_in[0];
    const float* ytrue = (const float*)d_in[1];
    float* out = (float*)d_out;

    unsigned short* gpk = (unsigned short*)d_ws;            // NPIX u16 ((g<<1)|fg) = 4 MB
    unsigned* sumsD = (unsigned*)(gpk + NPIX);              // B*RC*W u32 = 128 KB
    unsigned* sumsU = sumsD + (size_t)B * RC * W;           // B*RC*W u32 = 128 KB
    float* rowpart = (float*)(sumsU + (size_t)B * RC * W);  // B*(H/G)*4 f32 = 16 KB

    col_two_level<<<B * 16 * RC, 512, 0, stream>>>(ytrue, gpk, sumsD, sumsU);
    row_fused<<<B * H / G, W, 0, stream>>>(gpk, sumsD, sumsU, ypred, rowpart);
    batch_final<<<1, 512, 0, stream>>>(rowpart, out);
}